// Round 5
// baseline (239.853 us; speedup 1.0000x reference)
//
#include <hip/hip_runtime.h>
#include <hip/hip_bf16.h>
#include <cstdint>

#define D_IN  4096
#define D_OUT 4096

typedef __attribute__((ext_vector_type(4)))  int   i32x4;
typedef __attribute__((ext_vector_type(16))) int   i32x16;

typedef const __attribute__((address_space(1))) unsigned g_u32;
typedef __attribute__((address_space(3))) unsigned       l_u32;

// ------- pass 1 (fused): blocks [0,1024) per-block max|W|; rest quant x -----
__global__ void prep_kernel(const float* __restrict__ W, int nw,
                            const float* __restrict__ x,
                            char* __restrict__ xq,
                            const float* __restrict__ xscale, int nx,
                            float* __restrict__ bmax) {
    int tid = threadIdx.x;
    if (blockIdx.x < 1024) {
        // grid-stride max|W| over 1024 blocks
        __shared__ float red[256];
        float m = 0.f;
        for (int i = (blockIdx.x * 256 + tid) * 4; i < nw; i += 1024 * 256 * 4) {
            float4 v = *(const float4*)(W + i);
            m = fmaxf(m, fmaxf(fmaxf(fabsf(v.x), fabsf(v.y)),
                               fmaxf(fabsf(v.z), fabsf(v.w))));
        }
        red[tid] = m; __syncthreads();
        for (int s = 128; s > 0; s >>= 1) {
            if (tid < s) red[tid] = fmaxf(red[tid], red[tid + s]);
            __syncthreads();
        }
        if (tid == 0) bmax[blockIdx.x] = red[0];
    } else {
        int i = ((blockIdx.x - 1024) * 256 + tid) * 4;
        if (i >= nx) return;
        float inv = 127.0f / fmaxf(xscale[0], 1e-8f);
        float4 v = *(const float4*)(x + i);
        char4 o;
        o.x = (char)fminf(fmaxf(rintf(v.x * inv), -127.f), 127.f);
        o.y = (char)fminf(fmaxf(rintf(v.y * inv), -127.f), 127.f);
        o.z = (char)fminf(fmaxf(rintf(v.z * inv), -127.f), 127.f);
        o.w = (char)fminf(fmaxf(rintf(v.w * inv), -127.f), 127.f);
        *(char4*)(xq + i) = o;
    }
}

// ------- pass 2: W (K x N) -> int8 transposed Wt (N x K); also publish ws ---
// Each block reduces the 1024 partial maxima (4 KB, L2-hot) itself; block
// (0,0) additionally publishes ws = max|W|/127 for the GEMM epilogue.
// W values are exact multiples of ws_ref; rint(W*127/max) recovers the code.
__global__ void convW_kernel(const float* __restrict__ W,
                             char* __restrict__ Wt,
                             const float* __restrict__ bmax,
                             float* __restrict__ wsp) {
    __shared__ float tile[32][33];
    __shared__ float red[1024];
    int lt = threadIdx.y * 32 + threadIdx.x;
    red[lt] = bmax[lt]; __syncthreads();
    for (int s = 512; s > 0; s >>= 1) {
        if (lt < s) red[lt] = fmaxf(red[lt], red[lt + s]);
        __syncthreads();
    }
    float wmax = red[0];
    float invws = 127.0f / wmax;
    if (lt == 0 && blockIdx.x == 0 && blockIdx.y == 0)
        wsp[0] = wmax * (1.0f / 127.0f);

    int n0 = blockIdx.x * 32, k0 = blockIdx.y * 32;
    tile[threadIdx.y][threadIdx.x] =
        W[(size_t)(k0 + threadIdx.y) * D_OUT + n0 + threadIdx.x];
    __syncthreads();
    Wt[(size_t)(n0 + threadIdx.y) * D_IN + k0 + threadIdx.x] =
        (char)rintf(tile[threadIdx.x][threadIdx.y] * invws);
}

// ------- pass 3: 256x256 int8 GEMM, 32x32x32 MFMA, 2-region K-tile ---------
// A : [M][K] i8, Bt : [N][K] i8, C : [M][N] f32 = i32acc * (sx*ws) + bias.
// BK = 128 B rows; staging/swizzle/vmcnt byte-identical to the verified R4
// kernel. Only ds_read column math + MFMA shape + epilogue mapping changed.
//  R1 (compute): barrier | STAGE B1(t+1)->nxt | {reads ks0-1, 16 MFMA}
//                | {reads ks2-3 (reuse regs), 16 MFMA}
//  R2 (publish): barrier | STAGE B0(t+2),A(t+2)->cur | s_waitcnt vmcnt(6)
__global__ __launch_bounds__(512, 2)
void gemm_kernel(const char* __restrict__ A,
                 const char* __restrict__ Bt,
                 const float* __restrict__ bias,
                 const float* __restrict__ xscale,
                 const float* __restrict__ wsp,
                 float* __restrict__ C, int M) {
    constexpr int K = D_IN, N = D_OUT;         // byte stride per row = K (i8)
    constexpr int NT = K / 128;                // 32 K-tiles of 128 elems
    __shared__ char lds[2 * 65536];            // 2 x (A 32KiB + B 32KiB)

    const int tid  = threadIdx.x;
    const int lane = tid & 63;
    const int wid  = tid >> 6;
    const int wr   = wid >> 2;                 // 0..1  (M)
    const int wc   = wid & 3;                  // 0..3  (N)

    // bijective XCD-aware block swizzle
    const int nTn = N / 256;
    const int nwg = gridDim.x;
    int bid = blockIdx.x;
    int q8 = nwg >> 3, r8 = nwg & 7;
    int xcd = bid & 7, idx = bid >> 3;
    int swz = (xcd < r8 ? xcd * (q8 + 1) : r8 * (q8 + 1) + (xcd - r8) * q8) + idx;
    const int tm = swz / nTn, tn = swz % nTn;
    const int row0 = tm * 256, col0 = tn * 256;

    // staging: LDS dest LINEAR; XOR involution sw = p ^ ((p>>7)&7)<<4 applied
    // to the global SOURCE address, matched by swizzled ds_reads.
    int srcOff[4], dstOff[4];
#pragma unroll
    for (int i = 0; i < 4; ++i) {
        int p  = (i * 512 + tid) * 16;
        int sw = p ^ (((p >> 7) & 7) << 4);
        dstOff[i] = p;
        srcOff[i] = (sw >> 7) * K + (sw & 127);
    }

    const char* srcA = A  + (size_t)row0 * K;
    const char* srcB = Bt + (size_t)col0 * K;
    char* ldsb = lds;

    auto STAGE4 = [&](const char* src, char* dst) {
#pragma unroll
        for (int i = 0; i < 4; ++i)
            __builtin_amdgcn_global_load_lds((g_u32*)(src + srcOff[i]),
                                             (l_u32*)(dst + dstOff[i]), 16, 0, 0);
    };
    auto STAGE2 = [&](const char* src, char* dst) {
#pragma unroll
        for (int i = 0; i < 2; ++i)
            __builtin_amdgcn_global_load_lds((g_u32*)(src + srcOff[i]),
                                             (l_u32*)(dst + dstOff[i]), 16, 0, 0);
    };

    // ---- prologue: tile0 full (8 loads) + tile1 {B0, A} (6 loads) ----
    STAGE2(srcB, ldsb + 32768);                        // B0(0) -> buf0
    STAGE4(srcA, ldsb);                                // A(0)  -> buf0
    STAGE2(srcB + 128 * K, ldsb + 32768 + 16384);      // B1(0) -> buf0
    STAGE2(srcB + 128,     ldsb + 65536 + 32768);      // B0(1) -> buf1
    STAGE4(srcA + 128,     ldsb + 65536);              // A(1)  -> buf1

    i32x16 acc[4][2];
#pragma unroll
    for (int m = 0; m < 4; ++m)
#pragma unroll
        for (int n = 0; n < 2; ++n)
#pragma unroll
            for (int r = 0; r < 16; ++r) acc[m][n][r] = 0;

    // 32x32x32 fragment addressing: row = base + (lane&31), per-lane k-slice
    // byte col = ks*32 + (lane>>5)*16, swizzled by XOR ((row&7)<<4).
    const int sw7 = (lane & 7) << 4;
    const int hi16 = (lane >> 5) * 16;
    int coff[4];
#pragma unroll
    for (int ks = 0; ks < 4; ++ks) coff[ks] = (ks * 32 + hi16) ^ sw7;
    const int aRow = (wr * 128 + (lane & 31)) * 128;   // byte base in A region
    const int bRow = (wc * 64  + (lane & 31)) * 128;   // byte base in B region

    asm volatile("s_waitcnt vmcnt(6)" ::: "memory");   // tile0 resident

    auto KITER = [&](int t, char* cur, char* nxt) {
        i32x4 a[4][2], b[2][2];
        const char* cA = cur;
        const char* cB = cur + 32768;

        // ================= region 1: compute =================
        __builtin_amdgcn_s_barrier();
        if (t + 1 < NT) STAGE2(srcB + 128 * K + (t + 1) * 128, nxt + 32768 + 16384);

        // ---- chunk 0: ks = 0,1 ----
#pragma unroll
        for (int n = 0; n < 2; ++n) {
            b[n][0] = *(const i32x4*)(cB + bRow + n * 4096 + coff[0]);
            b[n][1] = *(const i32x4*)(cB + bRow + n * 4096 + coff[1]);
        }
#pragma unroll
        for (int m = 0; m < 4; ++m) {
            a[m][0] = *(const i32x4*)(cA + aRow + m * 4096 + coff[0]);
            a[m][1] = *(const i32x4*)(cA + aRow + m * 4096 + coff[1]);
        }
        __builtin_amdgcn_s_setprio(1);
#pragma unroll
        for (int m = 0; m < 4; ++m)
#pragma unroll
            for (int n = 0; n < 2; ++n) {
                acc[m][n] = __builtin_amdgcn_mfma_i32_32x32x32_i8(a[m][0], b[n][0], acc[m][n], 0, 0, 0);
                acc[m][n] = __builtin_amdgcn_mfma_i32_32x32x32_i8(a[m][1], b[n][1], acc[m][n], 0, 0, 0);
            }
        __builtin_amdgcn_s_setprio(0);

        // ---- chunk 1: ks = 2,3 (reuse registers) ----
#pragma unroll
        for (int n = 0; n < 2; ++n) {
            b[n][0] = *(const i32x4*)(cB + bRow + n * 4096 + coff[2]);
            b[n][1] = *(const i32x4*)(cB + bRow + n * 4096 + coff[3]);
        }
#pragma unroll
        for (int m = 0; m < 4; ++m) {
            a[m][0] = *(const i32x4*)(cA + aRow + m * 4096 + coff[2]);
            a[m][1] = *(const i32x4*)(cA + aRow + m * 4096 + coff[3]);
        }
        __builtin_amdgcn_s_setprio(1);
#pragma unroll
        for (int m = 0; m < 4; ++m)
#pragma unroll
            for (int n = 0; n < 2; ++n) {
                acc[m][n] = __builtin_amdgcn_mfma_i32_32x32x32_i8(a[m][0], b[n][0], acc[m][n], 0, 0, 0);
                acc[m][n] = __builtin_amdgcn_mfma_i32_32x32x32_i8(a[m][1], b[n][1], acc[m][n], 0, 0, 0);
            }
        __builtin_amdgcn_s_setprio(0);

        // ================= region 2: publish =================
        __builtin_amdgcn_s_barrier();
        if (t + 2 < NT) {
            STAGE2(srcB + (t + 2) * 128, cur + 32768);     // B0(t+2) -> cur
            STAGE4(srcA + (t + 2) * 128, cur);             // A (t+2) -> cur
            asm volatile("s_waitcnt vmcnt(6)" ::: "memory");
        } else {
            asm volatile("s_waitcnt vmcnt(0)" ::: "memory");
        }
    };

    for (int t = 0; t < NT; t += 2) {
        KITER(t,     ldsb,         ldsb + 65536);
        KITER(t + 1, ldsb + 65536, ldsb);
    }

    // ---- epilogue: C = acc * (sx*ws) + bias ----
    // 32x32 C/D layout: col = lane&31, row = (reg&3) + 8*(reg>>2) + 4*(lane>>5)
    const float scale = (fmaxf(xscale[0], 1e-8f) * (1.0f / 127.0f)) * wsp[0];
    const int lc = lane & 31, lr = 4 * (lane >> 5);
#pragma unroll
    for (int n = 0; n < 2; ++n) {
        int col = col0 + wc * 64 + n * 32 + lc;
        float bv = bias[col];
#pragma unroll
        for (int m = 0; m < 4; ++m) {
            int rowb = row0 + wr * 128 + m * 32 + lr;
            i32x16 v = acc[m][n];
#pragma unroll
            for (int reg = 0; reg < 16; ++reg) {
                int r = (reg & 3) + 8 * (reg >> 2);
                C[(size_t)(rowb + r) * N + col] = (float)v[reg] * scale + bv;
            }
        }
    }
}

extern "C" void kernel_launch(void* const* d_in, const int* in_sizes, int n_in,
                              void* d_out, int out_size, void* d_ws, size_t ws_size,
                              hipStream_t stream) {
    const float* x      = (const float*)d_in[0];   // [4,2048,4096] f32
    const float* W      = (const float*)d_in[1];   // [4096,4096] f32
    const float* xscale = (const float*)d_in[2];   // scalar
    const float* bias   = (const float*)d_in[3];   // [4096] f32
    float* out = (float*)d_out;

    const int nx = in_sizes[0];            // 33554432
    const int nw = in_sizes[1];            // 16777216
    const int M  = nx / D_IN;              // 8192

    char*  xq   = (char*)d_ws;                                  // 32 MiB
    char*  Wt   = (char*)d_ws + (size_t)nx;                     // 16 MiB
    float* bmax = (float*)((char*)d_ws + (size_t)nx + nw);      // 4 KiB
    float* wsp  = bmax + 1024;                                  // 4 B

    // fused: W-max partials (blocks 0..1023) + x quantization (rest)
    int qblocks = nx / 4 / 256;            // 32768
    prep_kernel<<<1024 + qblocks, 256, 0, stream>>>(W, nw, x, xq, xscale, nx, bmax);

    dim3 tb(32, 32);
    dim3 tg(D_OUT / 32, D_IN / 32);
    convW_kernel<<<tg, tb, 0, stream>>>(W, Wt, bmax, wsp);

    int grid = (M / 256) * (D_OUT / 256);  // 512
    gemm_kernel<<<grid, 512, 0, stream>>>(xq, Wt, bias, xscale, wsp, out, M);
}

// Round 6
// 216.034 us; speedup vs baseline: 1.1103x; 1.1103x over previous
//
#include <hip/hip_runtime.h>
#include <hip/hip_bf16.h>
#include <cstdint>

#define D_IN  4096
#define D_OUT 4096

typedef __attribute__((ext_vector_type(4)))  int   i32x4;

typedef const __attribute__((address_space(1))) unsigned g_u32;
typedef __attribute__((address_space(3))) unsigned       l_u32;

// ------- pass 1 (fused): blocks [0,1024) per-block max|W|; rest quant x -----
__global__ void prep_kernel(const float* __restrict__ W, int nw,
                            const float* __restrict__ x,
                            char* __restrict__ xq,
                            const float* __restrict__ xscale, int nx,
                            float* __restrict__ bmax) {
    int tid = threadIdx.x;
    if (blockIdx.x < 1024) {
        __shared__ float red[256];
        float m = 0.f;
        for (int i = (blockIdx.x * 256 + tid) * 4; i < nw; i += 1024 * 256 * 4) {
            float4 v = *(const float4*)(W + i);
            m = fmaxf(m, fmaxf(fmaxf(fabsf(v.x), fabsf(v.y)),
                               fmaxf(fabsf(v.z), fabsf(v.w))));
        }
        red[tid] = m; __syncthreads();
        for (int s = 128; s > 0; s >>= 1) {
            if (tid < s) red[tid] = fmaxf(red[tid], red[tid + s]);
            __syncthreads();
        }
        if (tid == 0) bmax[blockIdx.x] = red[0];
    } else {
        int i = ((blockIdx.x - 1024) * 256 + tid) * 4;
        if (i >= nx) return;
        float inv = 127.0f / fmaxf(xscale[0], 1e-8f);
        float4 v = *(const float4*)(x + i);
        char4 o;
        o.x = (char)fminf(fmaxf(rintf(v.x * inv), -127.f), 127.f);
        o.y = (char)fminf(fmaxf(rintf(v.y * inv), -127.f), 127.f);
        o.z = (char)fminf(fmaxf(rintf(v.z * inv), -127.f), 127.f);
        o.w = (char)fminf(fmaxf(rintf(v.w * inv), -127.f), 127.f);
        *(char4*)(xq + i) = o;
    }
}

// ------- pass 1b: ws = max(bmax) / 127 (single tiny block) ------------------
__global__ void wmax2_kernel(const float* __restrict__ bmax,
                             float* __restrict__ ws) {
    __shared__ float red[1024];
    int tid = threadIdx.x;
    red[tid] = bmax[tid]; __syncthreads();
    for (int s = 512; s > 0; s >>= 1) {
        if (tid < s) red[tid] = fmaxf(red[tid], red[tid + s]);
        __syncthreads();
    }
    if (tid == 0) ws[0] = red[0] * (1.0f / 127.0f);
}

// ------- pass 2: W (K x N) -> int8 transposed Wt (N x K) --------------------
__global__ void convW_kernel(const float* __restrict__ W,
                             char* __restrict__ Wt,
                             const float* __restrict__ ws) {
    __shared__ float tile[32][33];
    float invws = 1.0f / ws[0];
    int n0 = blockIdx.x * 32, k0 = blockIdx.y * 32;
    tile[threadIdx.y][threadIdx.x] =
        W[(size_t)(k0 + threadIdx.y) * D_OUT + n0 + threadIdx.x];
    __syncthreads();
    Wt[(size_t)(n0 + threadIdx.y) * D_IN + k0 + threadIdx.x] =
        (char)rintf(tile[threadIdx.x][threadIdx.y] * invws);
}

// ------- pass 3: 256x256 int8 GEMM, BK=64, reads-one-phase-ahead ------------
// A:[M][K] i8, Bt:[N][K] i8, C = i32acc * (sx*ws) + bias.
// NT=64 tiles of 64B. Per tile t, 2 phases (m201 discipline):
//  P1: read a47(cur) | stage B(t+2)->cur | bar | lgkm0 | Q1: aA x bUse (m0-3)
//      | vmcnt(2) [t+1 resident] | bar
//  P2: read a03(nxt), b(nxt) | stage A(t+2)->cur | bar | lgkm0
//      | Q2: aB x bUse (m4-7) | bar
// Race ledger: every phase's lgkm0+trailing-bar drains ALL waves' reads before
// any later staging overwrite (A: last read P1, staged P2; B: last read
// P2(t-1), staged P1(t)). vmcnt(2) leaves only B(t+2)'s 2 loads -> t+1 fully
// resident before P2 reads it. Swizzle: 64B rows, involution
// p ^= ((p>>6)&3)<<4 on SOURCE; reads use chunk ^= (lane&3).
__global__ __launch_bounds__(512, 2)
void gemm_kernel(const char* __restrict__ A,
                 const char* __restrict__ Bt,
                 const float* __restrict__ bias,
                 const float* __restrict__ xscale,
                 const float* __restrict__ wsp,
                 float* __restrict__ C, int M) {
    constexpr int K = D_IN, N = D_OUT;
    constexpr int NT = K / 64;                 // 64 K-tiles of 64 B
    __shared__ char lds[2 * 32768];            // buf k: A 16KB @ +0, B 16KB @ +16384

    const int tid  = threadIdx.x;
    const int lane = tid & 63;
    const int wid  = tid >> 6;
    const int wr   = wid >> 2;                 // 0..1  (M)
    const int wc   = wid & 3;                  // 0..3  (N)

    // bijective XCD-aware block swizzle
    const int nTn = N / 256;
    const int nwg = gridDim.x;
    int bid = blockIdx.x;
    int q8 = nwg >> 3, r8 = nwg & 7;
    int xcd = bid & 7, idx = bid >> 3;
    int swz = (xcd < r8 ? xcd * (q8 + 1) : r8 * (q8 + 1) + (xcd - r8) * q8) + idx;
    const int tm = swz / nTn, tn = swz % nTn;
    const int row0 = tm * 256, col0 = tn * 256;

    // staging offsets: LDS dest LINEAR; XOR involution on SOURCE
    int srcOff[2], dstOff[2];
#pragma unroll
    for (int i = 0; i < 2; ++i) {
        int p  = (i * 512 + tid) * 16;         // [0, 16384)
        int sw = p ^ (((p >> 6) & 3) << 4);
        dstOff[i] = p;
        srcOff[i] = (sw >> 6) * K + (sw & 63);
    }

    const char* srcA = A  + (size_t)row0 * K;
    const char* srcB = Bt + (size_t)col0 * K;
    char* b0 = lds;
    char* b1 = lds + 32768;

    auto STAGEA = [&](int t, char* buf) {      // 16KB: A rows 256 x 64B
#pragma unroll
        for (int i = 0; i < 2; ++i)
            __builtin_amdgcn_global_load_lds((g_u32*)(srcA + t * 64 + srcOff[i]),
                                             (l_u32*)(buf + dstOff[i]), 16, 0, 0);
    };
    auto STAGEB = [&](int t, char* buf) {      // 16KB: B rows 256 x 64B
#pragma unroll
        for (int i = 0; i < 2; ++i)
            __builtin_amdgcn_global_load_lds((g_u32*)(srcB + t * 64 + srcOff[i]),
                                             (l_u32*)(buf + 16384 + dstOff[i]), 16, 0, 0);
    };

    // ---- prologue: A0,B0 (4 loads), B1,A1 (4 loads) ----
    STAGEA(0, b0); STAGEB(0, b0);
    STAGEB(1, b1); STAGEA(1, b1);

    i32x4 acc[8][4];
#pragma unroll
    for (int m = 0; m < 8; ++m)
#pragma unroll
        for (int n = 0; n < 4; ++n) acc[m][n] = (i32x4){0, 0, 0, 0};

    // per-lane read addressing: row base x 64B + swizzled 16B chunk
    const int cOff  = (((lane >> 4) ^ (lane & 3)) << 4);
    const int aBase = (wr * 128 + (lane & 15)) * 64 + cOff;
    const int bBase = 16384 + (wc * 64 + (lane & 15)) * 64 + cOff;

    i32x4 aA[4], aB[4], bE[4], bO[4];

    asm volatile("s_waitcnt vmcnt(4)" ::: "memory");   // tile0 resident
    __builtin_amdgcn_s_barrier();
    // prologue reads: a03(t0), b(t0)
#pragma unroll
    for (int m = 0; m < 4; ++m) aA[m] = *(const i32x4*)(b0 + aBase + m * 1024);
#pragma unroll
    for (int n = 0; n < 4; ++n) bE[n] = *(const i32x4*)(b0 + bBase + n * 1024);
    asm volatile("s_waitcnt lgkmcnt(0)" ::: "memory"); // drain before t=0 staging
    __builtin_amdgcn_s_barrier();

    auto KTILE = [&](int t, char* cur, char* nxt, i32x4* bUse, i32x4* bLoad) {
        // ---------------- P1 ----------------
#pragma unroll
        for (int m = 0; m < 4; ++m) aB[m] = *(const i32x4*)(cur + aBase + 4096 + m * 1024);
        bool st = (t + 2 < NT);
        if (st) STAGEB(t + 2, cur);
        __builtin_amdgcn_s_barrier();
        asm volatile("s_waitcnt lgkmcnt(0)" ::: "memory");
        __builtin_amdgcn_s_setprio(1);
#pragma unroll
        for (int m = 0; m < 4; ++m)
#pragma unroll
            for (int n = 0; n < 4; ++n)
                acc[m][n] = __builtin_amdgcn_mfma_i32_16x16x64_i8(aA[m], bUse[n], acc[m][n], 0, 0, 0);
        __builtin_amdgcn_s_setprio(0);
        if (st) { asm volatile("s_waitcnt vmcnt(2)" ::: "memory"); }
        else    { asm volatile("s_waitcnt vmcnt(0)" ::: "memory"); }
        __builtin_amdgcn_s_barrier();

        // ---------------- P2 ----------------
        if (t + 1 < NT) {
#pragma unroll
            for (int m = 0; m < 4; ++m) aA[m] = *(const i32x4*)(nxt + aBase + m * 1024);
#pragma unroll
            for (int n = 0; n < 4; ++n) bLoad[n] = *(const i32x4*)(nxt + bBase + n * 1024);
        }
        if (st) STAGEA(t + 2, cur);
        __builtin_amdgcn_s_barrier();
        asm volatile("s_waitcnt lgkmcnt(0)" ::: "memory");
        __builtin_amdgcn_s_setprio(1);
#pragma unroll
        for (int m = 0; m < 4; ++m)
#pragma unroll
            for (int n = 0; n < 4; ++n)
                acc[m + 4][n] = __builtin_amdgcn_mfma_i32_16x16x64_i8(aB[m], bUse[n], acc[m + 4][n], 0, 0, 0);
        __builtin_amdgcn_s_setprio(0);
        __builtin_amdgcn_s_barrier();
    };

    for (int t = 0; t < NT; t += 2) {
        KTILE(t,     b0, b1, bE, bO);
        KTILE(t + 1, b1, b0, bO, bE);
    }

    // ---- epilogue: C = acc * (sx*ws) + bias ----
    const float scale = (fmaxf(xscale[0], 1e-8f) * (1.0f / 127.0f)) * wsp[0];
    const int lr = (lane >> 4) * 4, lc = lane & 15;
#pragma unroll
    for (int n = 0; n < 4; ++n) {
        int col = col0 + wc * 64 + n * 16 + lc;
        float bv = bias[col];
#pragma unroll
        for (int m = 0; m < 8; ++m) {
            int rowb = row0 + wr * 128 + m * 16 + lr;
            i32x4 v = acc[m][n];
#pragma unroll
            for (int r2 = 0; r2 < 4; ++r2)
                C[(size_t)(rowb + r2) * N + col] = (float)v[r2] * scale + bv;
        }
    }
}

extern "C" void kernel_launch(void* const* d_in, const int* in_sizes, int n_in,
                              void* d_out, int out_size, void* d_ws, size_t ws_size,
                              hipStream_t stream) {
    const float* x      = (const float*)d_in[0];   // [4,2048,4096] f32
    const float* W      = (const float*)d_in[1];   // [4096,4096] f32
    const float* xscale = (const float*)d_in[2];   // scalar
    const float* bias   = (const float*)d_in[3];   // [4096] f32
    float* out = (float*)d_out;

    const int nx = in_sizes[0];            // 33554432
    const int nw = in_sizes[1];            // 16777216
    const int M  = nx / D_IN;              // 8192

    char*  xq   = (char*)d_ws;                                  // 32 MiB
    char*  Wt   = (char*)d_ws + (size_t)nx;                     // 16 MiB
    float* bmax = (float*)((char*)d_ws + (size_t)nx + nw);      // 4 KiB
    float* wsp  = bmax + 1024;                                  // 4 B

    int qblocks = nx / 4 / 256;            // 32768
    prep_kernel<<<1024 + qblocks, 256, 0, stream>>>(W, nw, x, xq, xscale, nx, bmax);
    wmax2_kernel<<<1, 1024, 0, stream>>>(bmax, wsp);

    dim3 tb(32, 32);
    dim3 tg(D_OUT / 32, D_IN / 32);
    convW_kernel<<<tg, tb, 0, stream>>>(W, Wt, wsp);

    int grid = (M / 256) * (D_OUT / 256);  // 512
    gemm_kernel<<<grid, 512, 0, stream>>>(xq, Wt, bias, xscale, wsp, out, M);
}

// Round 7
// 206.413 us; speedup vs baseline: 1.1620x; 1.0466x over previous
//
#include <hip/hip_runtime.h>
#include <hip/hip_bf16.h>
#include <cstdint>

#define D_IN  4096
#define D_OUT 4096

typedef __attribute__((ext_vector_type(4)))  int   i32x4;

typedef const __attribute__((address_space(1))) unsigned g_u32;
typedef __attribute__((address_space(3))) unsigned       l_u32;

// ------- pass 1 (fused): blocks [0,1024) per-block max|W|; rest quant x -----
__global__ void prep_kernel(const float* __restrict__ W, int nw,
                            const float* __restrict__ x,
                            char* __restrict__ xq,
                            const float* __restrict__ xscale, int nx,
                            float* __restrict__ bmax) {
    int tid = threadIdx.x;
    if (blockIdx.x < 1024) {
        __shared__ float red[256];
        float m = 0.f;
        for (int i = (blockIdx.x * 256 + tid) * 4; i < nw; i += 1024 * 256 * 4) {
            float4 v = *(const float4*)(W + i);
            m = fmaxf(m, fmaxf(fmaxf(fabsf(v.x), fabsf(v.y)),
                               fmaxf(fabsf(v.z), fabsf(v.w))));
        }
        red[tid] = m; __syncthreads();
        for (int s = 128; s > 0; s >>= 1) {
            if (tid < s) red[tid] = fmaxf(red[tid], red[tid + s]);
            __syncthreads();
        }
        if (tid == 0) bmax[blockIdx.x] = red[0];
    } else {
        int i = ((blockIdx.x - 1024) * 256 + tid) * 4;
        if (i >= nx) return;
        float inv = 127.0f / fmaxf(xscale[0], 1e-8f);
        float4 v = *(const float4*)(x + i);
        char4 o;
        o.x = (char)fminf(fmaxf(rintf(v.x * inv), -127.f), 127.f);
        o.y = (char)fminf(fmaxf(rintf(v.y * inv), -127.f), 127.f);
        o.z = (char)fminf(fmaxf(rintf(v.z * inv), -127.f), 127.f);
        o.w = (char)fminf(fmaxf(rintf(v.w * inv), -127.f), 127.f);
        *(char4*)(xq + i) = o;
    }
}

// ------- pass 1b: ws = max(bmax) / 127 (single tiny block) ------------------
__global__ void wmax2_kernel(const float* __restrict__ bmax,
                             float* __restrict__ ws) {
    __shared__ float red[1024];
    int tid = threadIdx.x;
    red[tid] = bmax[tid]; __syncthreads();
    for (int s = 512; s > 0; s >>= 1) {
        if (tid < s) red[tid] = fmaxf(red[tid], red[tid + s]);
        __syncthreads();
    }
    if (tid == 0) ws[0] = red[0] * (1.0f / 127.0f);
}

// ------- pass 2: W (K x N) -> int8 transposed Wt (N x K) --------------------
// W values are exact multiples of ws; rint(W/ws) recovers the int8 code.
__global__ void convW_kernel(const float* __restrict__ W,
                             char* __restrict__ Wt,
                             const float* __restrict__ ws) {
    __shared__ float tile[32][33];
    float invws = 1.0f / ws[0];
    int n0 = blockIdx.x * 32, k0 = blockIdx.y * 32;
    tile[threadIdx.y][threadIdx.x] =
        W[(size_t)(k0 + threadIdx.y) * D_OUT + n0 + threadIdx.x];
    __syncthreads();
    Wt[(size_t)(n0 + threadIdx.y) * D_IN + k0 + threadIdx.x] =
        (char)rintf(tile[threadIdx.x][threadIdx.y] * invws);
}

// ------- pass 3: 256x256 int8 GEMM, 2-region K-tile (R4 structure) ---------
// A : [M][K] i8, Bt : [N][K] i8, C : [M][N] f32 = i32acc * (sx*ws) + bias.
// BK = 128 i8 elems = 128 B rows; NT = 32.
//  R1 (compute): barrier | STAGE B1(t+1)->nxt | ds_read b01,a03,b23 | Q1,Q2
//                | ds_read a47 (reuse regs) | Q3,Q4
//  R2 (publish): barrier | STAGE B0(t+2),A(t+2)->cur | s_waitcnt vmcnt(6)
// vmcnt(6) leaves exactly {B0(t+2),A(t+2)}: tile t+1 fully resident.
// Read swizzle: chunk = (lane>>4) ^ (lane&7); per quarter-wave this covers
// all 8 16B-chunks of a 128B row -> conflict-free (measured 0).
__global__ __launch_bounds__(512, 2)
void gemm_kernel(const char* __restrict__ A,
                 const char* __restrict__ Bt,
                 const float* __restrict__ bias,
                 const float* __restrict__ xscale,
                 const float* __restrict__ wsp,
                 float* __restrict__ C, int M) {
    constexpr int K = D_IN, N = D_OUT;         // byte stride per row = K (i8)
    constexpr int NT = K / 128;                // 32 K-tiles of 128 elems
    __shared__ char lds[2 * 65536];            // 2 x (A 32KiB + B 32KiB)

    const int tid  = threadIdx.x;
    const int lane = tid & 63;
    const int wid  = tid >> 6;
    const int wr   = wid >> 2;                 // 0..1  (M)
    const int wc   = wid & 3;                  // 0..3  (N)

    // bijective XCD-aware block swizzle
    const int nTn = N / 256;
    const int nwg = gridDim.x;
    int bid = blockIdx.x;
    int q8 = nwg >> 3, r8 = nwg & 7;
    int xcd = bid & 7, idx = bid >> 3;
    int swz = (xcd < r8 ? xcd * (q8 + 1) : r8 * (q8 + 1) + (xcd - r8) * q8) + idx;
    const int tm = swz / nTn, tn = swz % nTn;
    const int row0 = tm * 256, col0 = tn * 256;

    // staging: LDS dest LINEAR; XOR involution sw = p ^ ((p>>7)&7)<<4 applied
    // to the global SOURCE address, matched by swizzled ds_reads.
    int srcOff[4], dstOff[4];
#pragma unroll
    for (int i = 0; i < 4; ++i) {
        int p  = (i * 512 + tid) * 16;
        int sw = p ^ (((p >> 7) & 7) << 4);
        dstOff[i] = p;
        srcOff[i] = (sw >> 7) * K + (sw & 127);
    }

    const char* srcA = A  + (size_t)row0 * K;
    const char* srcB = Bt + (size_t)col0 * K;
    char* ldsb = lds;

    auto STAGE4 = [&](const char* src, char* dst) {
#pragma unroll
        for (int i = 0; i < 4; ++i)
            __builtin_amdgcn_global_load_lds((g_u32*)(src + srcOff[i]),
                                             (l_u32*)(dst + dstOff[i]), 16, 0, 0);
    };
    auto STAGE2 = [&](const char* src, char* dst) {
#pragma unroll
        for (int i = 0; i < 2; ++i)
            __builtin_amdgcn_global_load_lds((g_u32*)(src + srcOff[i]),
                                             (l_u32*)(dst + dstOff[i]), 16, 0, 0);
    };

    // ---- prologue: tile0 full (8 loads) + tile1 {B0, A} (6 loads) ----
    STAGE2(srcB, ldsb + 32768);                        // B0(0) -> buf0
    STAGE4(srcA, ldsb);                                // A(0)  -> buf0
    STAGE2(srcB + 128 * K, ldsb + 32768 + 16384);      // B1(0) -> buf0
    STAGE2(srcB + 128,     ldsb + 65536 + 32768);      // B0(1) -> buf1
    STAGE4(srcA + 128,     ldsb + 65536);              // A(1)  -> buf1

    i32x4 acc[8][4];
#pragma unroll
    for (int m = 0; m < 8; ++m)
#pragma unroll
        for (int n = 0; n < 4; ++n) acc[m][n] = (i32x4){0, 0, 0, 0};

    // swizzled per-lane read bases (chunk XOR covers row&7)
    const int cp0 = (((lane >> 4) << 4)) ^ ((lane & 7) << 4);
    const int cp1 = cp0 ^ 64;                          // k-half 1
    const int aBase = (wr * 128 + (lane & 15)) * 128;
    const int bBase = (wc * 64  + (lane & 15)) * 128;

    asm volatile("s_waitcnt vmcnt(6)" ::: "memory");   // tile0 resident

    auto KITER = [&](int t, char* cur, char* nxt) {
        i32x4 a[4][2], b01[2][2], b23[2][2];
        const char* cA = cur;
        const char* cB = cur + 32768;

        // ================= region 1: compute =================
        __builtin_amdgcn_s_barrier();
        if (t + 1 < NT) STAGE2(srcB + 128 * K + (t + 1) * 128, nxt + 32768 + 16384);

#pragma unroll
        for (int n = 0; n < 2; ++n) {
            b01[n][0] = *(const i32x4*)(cB + bBase + n * 2048 + cp0);
            b01[n][1] = *(const i32x4*)(cB + bBase + n * 2048 + cp1);
        }
#pragma unroll
        for (int m = 0; m < 4; ++m) {
            a[m][0] = *(const i32x4*)(cA + aBase + m * 2048 + cp0);
            a[m][1] = *(const i32x4*)(cA + aBase + m * 2048 + cp1);
        }
#pragma unroll
        for (int n = 0; n < 2; ++n) {
            b23[n][0] = *(const i32x4*)(cB + bBase + 4096 + n * 2048 + cp0);
            b23[n][1] = *(const i32x4*)(cB + bBase + 4096 + n * 2048 + cp1);
        }

        __builtin_amdgcn_s_setprio(1);
        // Q1: (m0-3, n0-1)
#pragma unroll
        for (int m = 0; m < 4; ++m)
#pragma unroll
            for (int n = 0; n < 2; ++n) {
                acc[m][n] = __builtin_amdgcn_mfma_i32_16x16x64_i8(a[m][0], b01[n][0], acc[m][n], 0, 0, 0);
                acc[m][n] = __builtin_amdgcn_mfma_i32_16x16x64_i8(a[m][1], b01[n][1], acc[m][n], 0, 0, 0);
            }
        // Q2: (m0-3, n2-3)
#pragma unroll
        for (int m = 0; m < 4; ++m)
#pragma unroll
            for (int n = 0; n < 2; ++n) {
                acc[m][n + 2] = __builtin_amdgcn_mfma_i32_16x16x64_i8(a[m][0], b23[n][0], acc[m][n + 2], 0, 0, 0);
                acc[m][n + 2] = __builtin_amdgcn_mfma_i32_16x16x64_i8(a[m][1], b23[n][1], acc[m][n + 2], 0, 0, 0);
            }
        // reload A rows 4-7 (reuse registers)
#pragma unroll
        for (int m = 0; m < 4; ++m) {
            a[m][0] = *(const i32x4*)(cA + aBase + 8192 + m * 2048 + cp0);
            a[m][1] = *(const i32x4*)(cA + aBase + 8192 + m * 2048 + cp1);
        }
        // Q3: (m4-7, n2-3)
#pragma unroll
        for (int m = 0; m < 4; ++m)
#pragma unroll
            for (int n = 0; n < 2; ++n) {
                acc[m + 4][n + 2] = __builtin_amdgcn_mfma_i32_16x16x64_i8(a[m][0], b23[n][0], acc[m + 4][n + 2], 0, 0, 0);
                acc[m + 4][n + 2] = __builtin_amdgcn_mfma_i32_16x16x64_i8(a[m][1], b23[n][1], acc[m + 4][n + 2], 0, 0, 0);
            }
        // Q4: (m4-7, n0-1)
#pragma unroll
        for (int m = 0; m < 4; ++m)
#pragma unroll
            for (int n = 0; n < 2; ++n) {
                acc[m + 4][n] = __builtin_amdgcn_mfma_i32_16x16x64_i8(a[m][0], b01[n][0], acc[m + 4][n], 0, 0, 0);
                acc[m + 4][n] = __builtin_amdgcn_mfma_i32_16x16x64_i8(a[m][1], b01[n][1], acc[m + 4][n], 0, 0, 0);
            }
        __builtin_amdgcn_s_setprio(0);

        // ================= region 2: publish =================
        __builtin_amdgcn_s_barrier();
        if (t + 2 < NT) {
            STAGE2(srcB + (t + 2) * 128, cur + 32768);     // B0(t+2) -> cur
            STAGE4(srcA + (t + 2) * 128, cur);             // A (t+2) -> cur
            asm volatile("s_waitcnt vmcnt(6)" ::: "memory");
        } else {
            asm volatile("s_waitcnt vmcnt(0)" ::: "memory");
        }
    };

    for (int t = 0; t < NT; t += 2) {
        KITER(t,     ldsb,         ldsb + 65536);
        KITER(t + 1, ldsb + 65536, ldsb);
    }

    // ---- epilogue: C = acc * (sx*ws) + bias ----
    const float scale = (fmaxf(xscale[0], 1e-8f) * (1.0f / 127.0f)) * wsp[0];
    const int lr = (lane >> 4) * 4, lc = lane & 15;
#pragma unroll
    for (int n = 0; n < 4; ++n) {
        int col = col0 + wc * 64 + n * 16 + lc;
        float bv = bias[col];
#pragma unroll
        for (int m = 0; m < 8; ++m) {
            int rowb = row0 + wr * 128 + m * 16 + lr;
            i32x4 v = acc[m][n];
#pragma unroll
            for (int r2 = 0; r2 < 4; ++r2)
                C[(size_t)(rowb + r2) * N + col] = (float)v[r2] * scale + bv;
        }
    }
}

extern "C" void kernel_launch(void* const* d_in, const int* in_sizes, int n_in,
                              void* d_out, int out_size, void* d_ws, size_t ws_size,
                              hipStream_t stream) {
    const float* x      = (const float*)d_in[0];   // [4,2048,4096] f32
    const float* W      = (const float*)d_in[1];   // [4096,4096] f32
    const float* xscale = (const float*)d_in[2];   // scalar
    const float* bias   = (const float*)d_in[3];   // [4096] f32
    float* out = (float*)d_out;

    const int nx = in_sizes[0];            // 33554432
    const int nw = in_sizes[1];            // 16777216
    const int M  = nx / D_IN;              // 8192

    char*  xq   = (char*)d_ws;                                  // 32 MiB
    char*  Wt   = (char*)d_ws + (size_t)nx;                     // 16 MiB
    float* bmax = (float*)((char*)d_ws + (size_t)nx + nw);      // 4 KiB
    float* wsp  = bmax + 1024;                                  // 4 B

    int qblocks = nx / 4 / 256;            // 32768
    prep_kernel<<<1024 + qblocks, 256, 0, stream>>>(W, nw, x, xq, xscale, nx, bmax);
    wmax2_kernel<<<1, 1024, 0, stream>>>(bmax, wsp);

    dim3 tb(32, 32);
    dim3 tg(D_OUT / 32, D_IN / 32);
    convW_kernel<<<tg, tb, 0, stream>>>(W, Wt, wsp);

    int grid = (M / 256) * (D_OUT / 256);  // 512
    gemm_kernel<<<grid, 512, 0, stream>>>(xq, Wt, bias, xscale, wsp, out, M);
}

// Round 8
// 200.591 us; speedup vs baseline: 1.1957x; 1.0290x over previous
//
#include <hip/hip_runtime.h>
#include <hip/hip_bf16.h>
#include <cstdint>

#define D_IN  4096
#define D_OUT 4096

typedef __attribute__((ext_vector_type(4)))  int   i32x4;

typedef const __attribute__((address_space(1))) unsigned g_u32;
typedef __attribute__((address_space(3))) unsigned       l_u32;

// ------- pass 1 (fused): blocks [0,1024) per-block max|W| -> atomicMax;
//         blocks [1024, ...) quantize x to int8 ------------------------------
// |W| >= 0 so float bit-pattern order == float order; atomicMax on uint is
// order-independent -> deterministic. wsp is zeroed per launch via memsetAsync.
__global__ void prep_kernel(const float* __restrict__ W, int nw,
                            const float* __restrict__ x,
                            char* __restrict__ xq,
                            const float* __restrict__ xscale, int nx,
                            unsigned* __restrict__ wsp) {
    int tid = threadIdx.x;
    if (blockIdx.x < 1024) {
        __shared__ float red[256];
        float m = 0.f;
        for (int i = (blockIdx.x * 256 + tid) * 4; i < nw; i += 1024 * 256 * 4) {
            float4 v = *(const float4*)(W + i);
            m = fmaxf(m, fmaxf(fmaxf(fabsf(v.x), fabsf(v.y)),
                               fmaxf(fabsf(v.z), fabsf(v.w))));
        }
        red[tid] = m; __syncthreads();
        for (int s = 128; s > 0; s >>= 1) {
            if (tid < s) red[tid] = fmaxf(red[tid], red[tid + s]);
            __syncthreads();
        }
        if (tid == 0) atomicMax(wsp, __float_as_uint(red[0]));
    } else {
        int i = ((blockIdx.x - 1024) * 256 + tid) * 4;
        if (i >= nx) return;
        float inv = 127.0f / fmaxf(xscale[0], 1e-8f);
        float4 v = *(const float4*)(x + i);
        char4 o;
        o.x = (char)fminf(fmaxf(rintf(v.x * inv), -127.f), 127.f);
        o.y = (char)fminf(fmaxf(rintf(v.y * inv), -127.f), 127.f);
        o.z = (char)fminf(fmaxf(rintf(v.z * inv), -127.f), 127.f);
        o.w = (char)fminf(fmaxf(rintf(v.w * inv), -127.f), 127.f);
        *(char4*)(xq + i) = o;
    }
}

// ------- pass 2: W (K x N) -> int8 transposed Wt (N x K), vectorized --------
// 64x64 tile per 256-thread block. Loads: 64B/thread contiguous f32; LDS
// [64][65] transpose (2-way bank = free); stores: packed 16B char16.
// W values are exact multiples of ws = max|W|/127; rint recovers the code.
__global__ void convW_kernel(const float* __restrict__ W,
                             char* __restrict__ Wt,
                             const unsigned* __restrict__ wsp) {
    __shared__ float tile[64][65];
    const float wmax = __uint_as_float(wsp[0]);
    const float inv  = 127.0f / wmax;
    const int n0 = blockIdx.x * 64, k0 = blockIdx.y * 64;
    const int t = threadIdx.x;

    // load: row r = t>>2 (k), cols (t&3)*16 .. +15 (n)
    {
        const int r = t >> 2, c0 = (t & 3) * 16;
        const float* src = W + (size_t)(k0 + r) * D_OUT + n0 + c0;
#pragma unroll
        for (int j = 0; j < 4; ++j) {
            float4 v = *(const float4*)(src + j * 4);
            tile[r][c0 + j * 4 + 0] = v.x;
            tile[r][c0 + j * 4 + 1] = v.y;
            tile[r][c0 + j * 4 + 2] = v.z;
            tile[r][c0 + j * 4 + 3] = v.w;
        }
    }
    __syncthreads();

    // store: row n = t>>2, k-chunk (t&3)*16 -> one 16B store
    {
        const int n = t >> 2, kc = (t & 3) * 16;
        int4 pk;
        int* pw = (int*)&pk;
#pragma unroll
        for (int w = 0; w < 4; ++w) {
            unsigned word = 0;
#pragma unroll
            for (int j = 0; j < 4; ++j) {
                int q = (int)rintf(tile[kc + w * 4 + j][n] * inv);
                word |= ((unsigned)(unsigned char)(char)q) << (8 * j);
            }
            pw[w] = (int)word;
        }
        *(int4*)(Wt + (size_t)(n0 + n) * D_IN + k0 + kc) = pk;
    }
}

// ------- pass 3: 256x256 int8 GEMM, 2-region K-tile (frozen R4/R7 GEMM) ----
// A : [M][K] i8, Bt : [N][K] i8, C : [M][N] f32 = i32acc * (sx*ws) + bias.
// BK = 128 i8 elems = 128 B rows; NT = 32.
//  R1 (compute): barrier | STAGE B1(t+1)->nxt | ds_read b01,a03,b23 | Q1,Q2
//                | ds_read a47 (reuse regs) | Q3,Q4
//  R2 (publish): barrier | STAGE B0(t+2),A(t+2)->cur | s_waitcnt vmcnt(6)
// vmcnt(6) leaves exactly {B0(t+2),A(t+2)}: tile t+1 fully resident.
// Read swizzle: chunk = (lane>>4) ^ (lane&7); per quarter-wave covers all 8
// 16B-chunks of a 128B row -> conflict-free (measured 0).
__global__ __launch_bounds__(512, 2)
void gemm_kernel(const char* __restrict__ A,
                 const char* __restrict__ Bt,
                 const float* __restrict__ bias,
                 const float* __restrict__ xscale,
                 const unsigned* __restrict__ wsp,
                 float* __restrict__ C, int M) {
    constexpr int K = D_IN, N = D_OUT;         // byte stride per row = K (i8)
    constexpr int NT = K / 128;                // 32 K-tiles of 128 elems
    __shared__ char lds[2 * 65536];            // 2 x (A 32KiB + B 32KiB)

    const int tid  = threadIdx.x;
    const int lane = tid & 63;
    const int wid  = tid >> 6;
    const int wr   = wid >> 2;                 // 0..1  (M)
    const int wc   = wid & 3;                  // 0..3  (N)

    // bijective XCD-aware block swizzle
    const int nTn = N / 256;
    const int nwg = gridDim.x;
    int bid = blockIdx.x;
    int q8 = nwg >> 3, r8 = nwg & 7;
    int xcd = bid & 7, idx = bid >> 3;
    int swz = (xcd < r8 ? xcd * (q8 + 1) : r8 * (q8 + 1) + (xcd - r8) * q8) + idx;
    const int tm = swz / nTn, tn = swz % nTn;
    const int row0 = tm * 256, col0 = tn * 256;

    // staging: LDS dest LINEAR; XOR involution sw = p ^ ((p>>7)&7)<<4 applied
    // to the global SOURCE address, matched by swizzled ds_reads.
    int srcOff[4], dstOff[4];
#pragma unroll
    for (int i = 0; i < 4; ++i) {
        int p  = (i * 512 + tid) * 16;
        int sw = p ^ (((p >> 7) & 7) << 4);
        dstOff[i] = p;
        srcOff[i] = (sw >> 7) * K + (sw & 127);
    }

    const char* srcA = A  + (size_t)row0 * K;
    const char* srcB = Bt + (size_t)col0 * K;
    char* ldsb = lds;

    auto STAGE4 = [&](const char* src, char* dst) {
#pragma unroll
        for (int i = 0; i < 4; ++i)
            __builtin_amdgcn_global_load_lds((g_u32*)(src + srcOff[i]),
                                             (l_u32*)(dst + dstOff[i]), 16, 0, 0);
    };
    auto STAGE2 = [&](const char* src, char* dst) {
#pragma unroll
        for (int i = 0; i < 2; ++i)
            __builtin_amdgcn_global_load_lds((g_u32*)(src + srcOff[i]),
                                             (l_u32*)(dst + dstOff[i]), 16, 0, 0);
    };

    // ---- prologue: tile0 full (8 loads) + tile1 {B0, A} (6 loads) ----
    STAGE2(srcB, ldsb + 32768);                        // B0(0) -> buf0
    STAGE4(srcA, ldsb);                                // A(0)  -> buf0
    STAGE2(srcB + 128 * K, ldsb + 32768 + 16384);      // B1(0) -> buf0
    STAGE2(srcB + 128,     ldsb + 65536 + 32768);      // B0(1) -> buf1
    STAGE4(srcA + 128,     ldsb + 65536);              // A(1)  -> buf1

    i32x4 acc[8][4];
#pragma unroll
    for (int m = 0; m < 8; ++m)
#pragma unroll
        for (int n = 0; n < 4; ++n) acc[m][n] = (i32x4){0, 0, 0, 0};

    // swizzled per-lane read bases (chunk XOR covers row&7)
    const int cp0 = (((lane >> 4) << 4)) ^ ((lane & 7) << 4);
    const int cp1 = cp0 ^ 64;                          // k-half 1
    const int aBase = (wr * 128 + (lane & 15)) * 128;
    const int bBase = (wc * 64  + (lane & 15)) * 128;

    asm volatile("s_waitcnt vmcnt(6)" ::: "memory");   // tile0 resident

    auto KITER = [&](int t, char* cur, char* nxt) {
        i32x4 a[4][2], b01[2][2], b23[2][2];
        const char* cA = cur;
        const char* cB = cur + 32768;

        // ================= region 1: compute =================
        __builtin_amdgcn_s_barrier();
        if (t + 1 < NT) STAGE2(srcB + 128 * K + (t + 1) * 128, nxt + 32768 + 16384);

#pragma unroll
        for (int n = 0; n < 2; ++n) {
            b01[n][0] = *(const i32x4*)(cB + bBase + n * 2048 + cp0);
            b01[n][1] = *(const i32x4*)(cB + bBase + n * 2048 + cp1);
        }
#pragma unroll
        for (int m = 0; m < 4; ++m) {
            a[m][0] = *(const i32x4*)(cA + aBase + m * 2048 + cp0);
            a[m][1] = *(const i32x4*)(cA + aBase + m * 2048 + cp1);
        }
#pragma unroll
        for (int n = 0; n < 2; ++n) {
            b23[n][0] = *(const i32x4*)(cB + bBase + 4096 + n * 2048 + cp0);
            b23[n][1] = *(const i32x4*)(cB + bBase + 4096 + n * 2048 + cp1);
        }

        __builtin_amdgcn_s_setprio(1);
        // Q1: (m0-3, n0-1)
#pragma unroll
        for (int m = 0; m < 4; ++m)
#pragma unroll
            for (int n = 0; n < 2; ++n) {
                acc[m][n] = __builtin_amdgcn_mfma_i32_16x16x64_i8(a[m][0], b01[n][0], acc[m][n], 0, 0, 0);
                acc[m][n] = __builtin_amdgcn_mfma_i32_16x16x64_i8(a[m][1], b01[n][1], acc[m][n], 0, 0, 0);
            }
        // Q2: (m0-3, n2-3)
#pragma unroll
        for (int m = 0; m < 4; ++m)
#pragma unroll
            for (int n = 0; n < 2; ++n) {
                acc[m][n + 2] = __builtin_amdgcn_mfma_i32_16x16x64_i8(a[m][0], b23[n][0], acc[m][n + 2], 0, 0, 0);
                acc[m][n + 2] = __builtin_amdgcn_mfma_i32_16x16x64_i8(a[m][1], b23[n][1], acc[m][n + 2], 0, 0, 0);
            }
        // reload A rows 4-7 (reuse registers)
#pragma unroll
        for (int m = 0; m < 4; ++m) {
            a[m][0] = *(const i32x4*)(cA + aBase + 8192 + m * 2048 + cp0);
            a[m][1] = *(const i32x4*)(cA + aBase + 8192 + m * 2048 + cp1);
        }
        // Q3: (m4-7, n2-3)
#pragma unroll
        for (int m = 0; m < 4; ++m)
#pragma unroll
            for (int n = 0; n < 2; ++n) {
                acc[m + 4][n + 2] = __builtin_amdgcn_mfma_i32_16x16x64_i8(a[m][0], b23[n][0], acc[m + 4][n + 2], 0, 0, 0);
                acc[m + 4][n + 2] = __builtin_amdgcn_mfma_i32_16x16x64_i8(a[m][1], b23[n][1], acc[m + 4][n + 2], 0, 0, 0);
            }
        // Q4: (m4-7, n0-1)
#pragma unroll
        for (int m = 0; m < 4; ++m)
#pragma unroll
            for (int n = 0; n < 2; ++n) {
                acc[m + 4][n] = __builtin_amdgcn_mfma_i32_16x16x64_i8(a[m][0], b01[n][0], acc[m + 4][n], 0, 0, 0);
                acc[m + 4][n] = __builtin_amdgcn_mfma_i32_16x16x64_i8(a[m][1], b01[n][1], acc[m + 4][n], 0, 0, 0);
            }
        __builtin_amdgcn_s_setprio(0);

        // ================= region 2: publish =================
        __builtin_amdgcn_s_barrier();
        if (t + 2 < NT) {
            STAGE2(srcB + (t + 2) * 128, cur + 32768);     // B0(t+2) -> cur
            STAGE4(srcA + (t + 2) * 128, cur);             // A (t+2) -> cur
            asm volatile("s_waitcnt vmcnt(6)" ::: "memory");
        } else {
            asm volatile("s_waitcnt vmcnt(0)" ::: "memory");
        }
    };

    for (int t = 0; t < NT; t += 2) {
        KITER(t,     ldsb,         ldsb + 65536);
        KITER(t + 1, ldsb + 65536, ldsb);
    }

    // ---- epilogue: C = acc * (sx*ws) + bias, ws = max|W|/127 ----
    const float wmax  = __uint_as_float(wsp[0]);
    const float scale = (fmaxf(xscale[0], 1e-8f) * (1.0f / 127.0f)) * (wmax * (1.0f / 127.0f));
    const int lr = (lane >> 4) * 4, lc = lane & 15;
#pragma unroll
    for (int n = 0; n < 4; ++n) {
        int col = col0 + wc * 64 + n * 16 + lc;
        float bv = bias[col];
#pragma unroll
        for (int m = 0; m < 8; ++m) {
            int rowb = row0 + wr * 128 + m * 16 + lr;
            i32x4 v = acc[m][n];
#pragma unroll
            for (int r2 = 0; r2 < 4; ++r2)
                C[(size_t)(rowb + r2) * N + col] = (float)v[r2] * scale + bv;
        }
    }
}

extern "C" void kernel_launch(void* const* d_in, const int* in_sizes, int n_in,
                              void* d_out, int out_size, void* d_ws, size_t ws_size,
                              hipStream_t stream) {
    const float* x      = (const float*)d_in[0];   // [4,2048,4096] f32
    const float* W      = (const float*)d_in[1];   // [4096,4096] f32
    const float* xscale = (const float*)d_in[2];   // scalar
    const float* bias   = (const float*)d_in[3];   // [4096] f32
    float* out = (float*)d_out;

    const int nx = in_sizes[0];            // 33554432
    const int nw = in_sizes[1];            // 16777216
    const int M  = nx / D_IN;              // 8192

    char*     xq  = (char*)d_ws;                               // 32 MiB
    char*     Wt  = (char*)d_ws + (size_t)nx;                  // 16 MiB
    unsigned* wsp = (unsigned*)((char*)d_ws + (size_t)nx + nw);// 4 B

    // re-init the atomic max target every launch (deterministic; graph-safe)
    hipMemsetAsync(wsp, 0, 4, stream);

    int qblocks = nx / 4 / 256;            // 32768
    prep_kernel<<<1024 + qblocks, 256, 0, stream>>>(W, nw, x, xq, xscale, nx, wsp);

    dim3 tb(256);
    dim3 tg(D_OUT / 64, D_IN / 64);        // 64 x 64
    convW_kernel<<<tg, tb, 0, stream>>>(W, Wt, wsp);

    int grid = (M / 256) * (D_OUT / 256);  // 512
    gemm_kernel<<<grid, 512, 0, stream>>>(xq, Wt, bias, xscale, wsp, out, M);
}